// Round 9
// baseline (115.425 us; speedup 1.0000x reference)
//
#include <hip/hip_runtime.h>
#include <hip/hip_bf16.h>

#define B_ 4
#define N_ 2048
#define C_ 768
#define H_ 8
#define D_ 96

typedef __attribute__((ext_vector_type(8))) short bf16x8;
typedef __attribute__((ext_vector_type(2))) float f32x2;
typedef __attribute__((ext_vector_type(4))) float f32x4;
typedef __attribute__((ext_vector_type(16))) float f32x16;
typedef __attribute__((ext_vector_type(4))) unsigned u32x4;

static __device__ __forceinline__ unsigned cvtpk(float lo, float hi) {
  unsigned r;
  asm("v_cvt_pk_bf16_f32 %0, %1, %2" : "=v"(r) : "v"(lo), "v"(hi));
  return r;
}
static __device__ __forceinline__ float tof(short u) {
  return __bfloat162float(__builtin_bit_cast(__hip_bfloat16, (unsigned short)u));
}
static __device__ __forceinline__ void gload16(const void* g,
                                               const __attribute__((address_space(3))) short* l) {
  __builtin_amdgcn_global_load_lds(
      (const __attribute__((address_space(1))) void*)g,
      (__attribute__((address_space(3))) void*)l, 16, 0, 0);
}

// ---------------------------------------------------------------------------
// prep: cast x -> Xbf (bf16) and build Vtg (per-head d-major)
// ---------------------------------------------------------------------------
__global__ __launch_bounds__(64) void k_prep(const float* __restrict__ x,
                                             __hip_bfloat16* __restrict__ Xbf,
                                             __hip_bfloat16* __restrict__ Vtg) {
  const int t = threadIdx.x;
  const int nc = blockIdx.x, bh = blockIdx.y;
  const int b = bh >> 3, h = bh & 7;
  const int n = nc * 64 + t;
  const size_t rowoff = ((size_t)(b * N_ + n)) * C_ + h * D_;
  const float* src = x + rowoff;
  __hip_bfloat16* dx = Xbf + rowoff;
#pragma unroll
  for (int c8 = 0; c8 < 12; ++c8) {
    float4 lo = *(const float4*)(src + c8 * 8);
    float4 hi = *(const float4*)(src + c8 * 8 + 4);
    uint4 pk;
    pk.x = cvtpk(lo.x, lo.y);
    pk.y = cvtpk(lo.z, lo.w);
    pk.z = cvtpk(hi.x, hi.y);
    pk.w = cvtpk(hi.z, hi.w);
    *(uint4*)(dx + c8 * 8) = pk;
    unsigned short uu[8];
    uu[0] = (unsigned short)(pk.x & 0xffff); uu[1] = (unsigned short)(pk.x >> 16);
    uu[2] = (unsigned short)(pk.y & 0xffff); uu[3] = (unsigned short)(pk.y >> 16);
    uu[4] = (unsigned short)(pk.z & 0xffff); uu[5] = (unsigned short)(pk.z >> 16);
    uu[6] = (unsigned short)(pk.w & 0xffff); uu[7] = (unsigned short)(pk.w >> 16);
#pragma unroll
    for (int e = 0; e < 8; ++e) {
      __hip_bfloat16 hv = __builtin_bit_cast(__hip_bfloat16, uu[e]);
      Vtg[((size_t)(bh * D_ + c8 * 8 + e)) * N_ + n] = hv;
    }
  }
}

__global__ __launch_bounds__(256) void k_castw(const float* __restrict__ w,
                                               __hip_bfloat16* __restrict__ Wbf) {
  const int i = blockIdx.x * 256 + threadIdx.x;
  float4 f = *(const float4*)(w + (size_t)i * 4);
  uint2 pk;
  pk.x = cvtpk(f.x, f.y);
  pk.y = cvtpk(f.z, f.w);
  *(uint2*)(Wbf + (size_t)i * 4) = pk;
}

static __device__ __forceinline__ bf16x8 scale8(bf16x8 v, float s) {
  float f[8];
#pragma unroll
  for (int e = 0; e < 8; ++e) f[e] = tof(v[e]) * s;
  u32x4 pw;
  pw.x = cvtpk(f[0], f[1]);
  pw.y = cvtpk(f[2], f[3]);
  pw.z = cvtpk(f[4], f[5]);
  pw.w = cvtpk(f[6], f[7]);
  return __builtin_bit_cast(bf16x8, pw);
}

// ---------------------------------------------------------------------------
// flash attention v9: v8 structure + setprio around MFMA clusters + packed
// pair-sum for psum (breaks serial add chain, enables v_pk_add_f32).
// 8 waves = 4 q-subtiles x 2 kv-groups; q-tile 128; kv 64/iter via
// global_load_lds; 32x32x16 MFMA; in-reg P; no online max; LDS-combine.
// ---------------------------------------------------------------------------
__global__ __launch_bounds__(512, 4) void k_attn(const __hip_bfloat16* __restrict__ Xbf,
                                                 const __hip_bfloat16* __restrict__ Vtg,
                                                 __hip_bfloat16* __restrict__ Ybf) {
  __shared__ __align__(16) short SMs[27648];

  const int tid = threadIdx.x;
  const int wid = tid >> 6, lane = tid & 63;
  const int qsub = wid & 3, grp = wid >> 2;
  const int lr = lane & 31, hi = lane >> 5;
  const int qt = blockIdx.x, bh = blockIdx.y;
  const int b = bh >> 3, h = bh & 7;
  const int q0w = qt * 128 + qsub * 32;
  const float SL2E = 0.14724444f;  // log2(e)/sqrt(96)

  bf16x8 qf[6];
  {
    const __hip_bfloat16* qp =
        Xbf + ((size_t)(b * N_ + q0w + lr)) * C_ + h * D_ + hi * 8;
#pragma unroll
    for (int kk = 0; kk < 6; ++kk)
      qf[kk] = scale8(*(const bf16x8*)(qp + kk * 16), SL2E);
  }

  const short* Kbase = (const short*)(Xbf + ((size_t)b * N_) * C_ + h * D_);
  const short* Vbase = (const short*)(Vtg + ((size_t)bh * D_) * N_);

  const short* gsrc[4];
#pragma unroll
  for (int j = 0; j < 4; ++j) {
    const int t = wid + 8 * j;
    gsrc[j] = Kbase;
    if (t < 13) {
      int pc = t * 64 + lane;
      int r = pc / 13, ch = pc % 13;
      if (ch >= 12) ch = 0;
      gsrc[j] = Kbase + (size_t)r * C_ + ch * 8;
    } else if (t < 27) {
      int vc = t * 64 + lane - 832;
      int r = vc / 9, ch = vc % 9;
      if (vc >= 864) { r = 0; ch = 0; }
      if (ch >= 8) ch = 0;
      gsrc[j] = Vbase + (size_t)r * N_ + ch * 8;
    }
  }
  auto ldsb = (__attribute__((address_space(3))) short*)SMs;
  auto stage = [&](int nb) {
#pragma unroll
    for (int j = 0; j < 4; ++j) {
      const int t = wid + 8 * j;
      if (t < 27) {
        gload16(gsrc[j], ldsb + nb * 13824 + t * 512);
        gsrc[j] += (t < 13) ? 64 * C_ : 64;
      }
    }
  };

  stage(0);
  __syncthreads();

  f32x16 accO[3] = {};
  float lrun = 0.f;
  const int kro = (grp * 32 + lr) * 104 + hi * 8;
  const int vro = 6656 + lr * 72 + grp * 32 + hi * 8;

  int cur = 0;
  for (int it = 0; it < N_ / 64; ++it) {
    if (it < N_ / 64 - 1) stage(cur ^ 1);

    // --- S^T = K * Q^T ---
    const short* Kw = SMs + cur * 13824 + kro;
    f32x16 accS = {};
    __builtin_amdgcn_s_setprio(1);
#pragma unroll
    for (int kk = 0; kk < 6; ++kk) {
      bf16x8 kf = *(const bf16x8*)(Kw + kk * 16);
      accS = __builtin_amdgcn_mfma_f32_32x32x16_bf16(kf, qf[kk], accS, 0, 0, 0);
    }
    __builtin_amdgcn_s_setprio(0);

    // --- P = exp2(S'); packed pair-sum ---
#pragma unroll
    for (int r = 0; r < 16; ++r) accS[r] = exp2f(accS[r]);
    f32x2 psA = {0.f, 0.f}, psB = {0.f, 0.f};
#pragma unroll
    for (int r = 0; r < 16; r += 4) {
      f32x2 a; a.x = accS[r]; a.y = accS[r + 1];
      f32x2 c; c.x = accS[r + 2]; c.y = accS[r + 3];
      psA += a;
      psB += c;
    }
    psA += psB;
    lrun += psA.x + psA.y;

    // --- pack P to PV B-fragments in-register ---
    bf16x8 pbf[2];
#pragma unroll
    for (int s = 0; s < 2; ++s) {
      unsigned lo0 = cvtpk(accS[8 * s + 0], accS[8 * s + 1]);
      unsigned lo1 = cvtpk(accS[8 * s + 2], accS[8 * s + 3]);
      unsigned hi0 = cvtpk(accS[8 * s + 4], accS[8 * s + 5]);
      unsigned hi1 = cvtpk(accS[8 * s + 6], accS[8 * s + 7]);
      asm volatile("v_permlane32_swap_b32 %0, %1" : "+v"(lo0), "+v"(hi0));
      asm volatile("v_permlane32_swap_b32 %0, %1" : "+v"(lo1), "+v"(hi1));
      u32x4 pw;
      pw.x = lo0; pw.y = lo1; pw.z = hi0; pw.w = hi1;
      pbf[s] = __builtin_bit_cast(bf16x8, pw);
    }

    // --- O^T += V^T * P^T ---
    const short* Vw = SMs + cur * 13824 + vro;
    __builtin_amdgcn_s_setprio(1);
#pragma unroll
    for (int s = 0; s < 2; ++s) {
#pragma unroll
      for (int dt = 0; dt < 3; ++dt) {
        bf16x8 va = *(const bf16x8*)(Vw + dt * 32 * 72 + s * 16);
        accO[dt] = __builtin_amdgcn_mfma_f32_32x32x16_bf16(va, pbf[s], accO[dt], 0, 0, 0);
      }
    }
    __builtin_amdgcn_s_setprio(0);

    __syncthreads();
    cur ^= 1;
  }

  // --- epilogue: combine kv-group partials via LDS (exact additive) ---
  float* Osh = (float*)SMs;
  float* lsh = (float*)SMs + 12288;
  if (grp == 0) {
#pragma unroll
    for (int dt = 0; dt < 3; ++dt)
#pragma unroll
      for (int r = 0; r < 16; ++r) {
        int dloc = (r & 3) + 8 * (r >> 2) + 4 * hi;
        Osh[(qsub * 96 + dt * 32 + dloc) * 32 + lr] = accO[dt][r];
      }
    lsh[qsub * 64 + lane] = lrun;
  }
  __syncthreads();
  if (grp == 1) {
    lrun += lsh[qsub * 64 + lane];
    float ltot = lrun + __shfl_xor(lrun, 32);
    float linv = 1.0f / ltot;
    __hip_bfloat16* yb =
        Ybf + ((size_t)(b * N_ + q0w + lr)) * C_ + h * D_ + hi * 4;
#pragma unroll
    for (int dt = 0; dt < 3; ++dt) {
#pragma unroll
      for (int rg = 0; rg < 4; ++rg) {
        float v0 = (accO[dt][rg * 4 + 0] +
                    Osh[(qsub * 96 + dt * 32 + 8 * rg + 4 * hi + 0) * 32 + lr]) * linv;
        float v1 = (accO[dt][rg * 4 + 1] +
                    Osh[(qsub * 96 + dt * 32 + 8 * rg + 4 * hi + 1) * 32 + lr]) * linv;
        float v2 = (accO[dt][rg * 4 + 2] +
                    Osh[(qsub * 96 + dt * 32 + 8 * rg + 4 * hi + 2) * 32 + lr]) * linv;
        float v3 = (accO[dt][rg * 4 + 3] +
                    Osh[(qsub * 96 + dt * 32 + 8 * rg + 4 * hi + 3) * 32 + lr]) * linv;
        uint2 st;
        st.x = cvtpk(v0, v1);
        st.y = cvtpk(v2, v3);
        *(uint2*)(yb + dt * 32 + rg * 8) = st;
      }
    }
  }
}

// ---------------------------------------------------------------------------
// projection v2: 64x128 tile (3 blocks/CU, 12 waves/CU), n-tile-fast grid so
// consecutive blocks share the A row-panel in L2. 4 waves x (32x64).
// ---------------------------------------------------------------------------
__global__ __launch_bounds__(256) void k_proj(const __hip_bfloat16* __restrict__ Ybf,
                                              const __hip_bfloat16* __restrict__ Wbf,
                                              const float* __restrict__ bias,
                                              float* __restrict__ out) {
  __shared__ __hip_bfloat16 Alds[64][40];
  __shared__ __hip_bfloat16 Blds[128][40];
  const int tid = threadIdx.x, wid = tid >> 6, lane = tid & 63;
  const int lr = lane & 15, lg = lane >> 4;
  const int n0 = blockIdx.x * 128, m0 = blockIdx.y * 64;
  const int wm = (wid >> 1) * 32, wn = (wid & 1) * 64;

  const f32x4 fzero = {0.f, 0.f, 0.f, 0.f};
  f32x4 acc[2][4];
#pragma unroll
  for (int mi = 0; mi < 2; ++mi)
#pragma unroll
    for (int ni = 0; ni < 4; ++ni) acc[mi][ni] = fzero;

  for (int k0 = 0; k0 < C_; k0 += 32) {
    {
      int r = tid >> 2, cc = tid & 3;
      if (r < 64)
        *(bf16x8*)(&Alds[r][cc * 8]) =
            *(const bf16x8*)(Ybf + (size_t)(m0 + r) * C_ + k0 + cc * 8);
    }
#pragma unroll
    for (int i = 0; i < 2; ++i) {
      int idx = tid + i * 256;
      int r = idx >> 2, cc = idx & 3;
      *(bf16x8*)(&Blds[r][cc * 8]) =
          *(const bf16x8*)(Wbf + (size_t)(n0 + r) * C_ + k0 + cc * 8);
    }
    __syncthreads();
    bf16x8 af[2], bfr[4];
#pragma unroll
    for (int i = 0; i < 2; ++i)
      af[i] = *(const bf16x8*)(&Alds[wm + i * 16 + lr][lg * 8]);
#pragma unroll
    for (int i = 0; i < 4; ++i)
      bfr[i] = *(const bf16x8*)(&Blds[wn + i * 16 + lr][lg * 8]);
#pragma unroll
    for (int mi = 0; mi < 2; ++mi)
#pragma unroll
      for (int ni = 0; ni < 4; ++ni)
        acc[mi][ni] = __builtin_amdgcn_mfma_f32_16x16x32_bf16(af[mi], bfr[ni], acc[mi][ni], 0, 0, 0);
    __syncthreads();
  }

#pragma unroll
  for (int mi = 0; mi < 2; ++mi) {
#pragma unroll
    for (int ni = 0; ni < 4; ++ni) {
      int col = n0 + wn + ni * 16 + lr;
      float bv = bias[col];
#pragma unroll
      for (int j = 0; j < 4; ++j) {
        int row = m0 + wm + mi * 16 + lg * 4 + j;
        out[(size_t)row * C_ + col] = acc[mi][ni][j] + bv;
      }
    }
  }
}

extern "C" void kernel_launch(void* const* d_in, const int* in_sizes, int n_in,
                              void* d_out, int out_size, void* d_ws, size_t ws_size,
                              hipStream_t stream) {
  const float* x = (const float*)d_in[0];
  const float* pw = (const float*)d_in[1];
  const float* pb = (const float*)d_in[2];
  float* out = (float*)d_out;

  __hip_bfloat16* Xbf = (__hip_bfloat16*)d_ws;
  __hip_bfloat16* Vtg = Xbf + (size_t)B_ * N_ * C_;
  __hip_bfloat16* Wbf = Vtg + (size_t)B_ * N_ * C_;
  __hip_bfloat16* Ybf = Wbf + (size_t)C_ * C_;

  k_prep<<<dim3(N_ / 64, B_ * H_), 64, 0, stream>>>(x, Xbf, Vtg);
  k_castw<<<(C_ * C_ / 4) / 256, 256, 0, stream>>>(pw, Wbf);
  k_attn<<<dim3(N_ / 128, B_ * H_), 512, 0, stream>>>(Xbf, Vtg, Ybf);
  k_proj<<<dim3(C_ / 128, (B_ * N_) / 64), 256, 0, stream>>>(Ybf, Wbf, pb, out);
}

// Round 10
// 106.831 us; speedup vs baseline: 1.0804x; 1.0804x over previous
//
#include <hip/hip_runtime.h>
#include <hip/hip_bf16.h>

#define B_ 4
#define N_ 2048
#define C_ 768
#define H_ 8
#define D_ 96

typedef __attribute__((ext_vector_type(8))) short bf16x8;
typedef __attribute__((ext_vector_type(2))) float f32x2;
typedef __attribute__((ext_vector_type(4))) float f32x4;
typedef __attribute__((ext_vector_type(16))) float f32x16;
typedef __attribute__((ext_vector_type(4))) unsigned u32x4;

static __device__ __forceinline__ unsigned cvtpk(float lo, float hi) {
  unsigned r;
  asm("v_cvt_pk_bf16_f32 %0, %1, %2" : "=v"(r) : "v"(lo), "v"(hi));
  return r;
}
static __device__ __forceinline__ float tof(short u) {
  return __bfloat162float(__builtin_bit_cast(__hip_bfloat16, (unsigned short)u));
}
static __device__ __forceinline__ void gload16(const void* g,
                                               const __attribute__((address_space(3))) short* l) {
  __builtin_amdgcn_global_load_lds(
      (const __attribute__((address_space(1))) void*)g,
      (__attribute__((address_space(3))) void*)l, 16, 0, 0);
}

// ---------------------------------------------------------------------------
// prep v2: 256 threads/block, block = (64 n-rows, one bh).
// Phase A: read x (f32, float4 x2 per chunk), cvt to bf16, 16B store to Xbf,
//          scatter into padded LDS transpose tile T[96][73].
// Phase B: read T rows (d-major) as 16B chunks, 16B stores to Vtg.
// All global traffic vectorized 16-32B/lane.
// ---------------------------------------------------------------------------
__global__ __launch_bounds__(256) void k_prep(const float* __restrict__ x,
                                              __hip_bfloat16* __restrict__ Xbf,
                                              __hip_bfloat16* __restrict__ Vtg) {
  __shared__ short T[96 * 73];
  const int tid = threadIdx.x;
  const int nc = blockIdx.x, bh = blockIdx.y;
  const int b = bh >> 3, h = bh & 7;
  const int n0 = nc * 64;
  const float* xb = x + ((size_t)(b * N_ + n0)) * C_ + h * D_;
  __hip_bfloat16* xo = Xbf + ((size_t)(b * N_ + n0)) * C_ + h * D_;

#pragma unroll
  for (int i = 0; i < 3; ++i) {
    int c = tid + 256 * i;          // 0..767 chunk id
    int r = c / 12, c8 = c % 12;    // n-row r, 8-col group c8
    const float* src = xb + (size_t)r * C_ + c8 * 8;
    float4 lo = *(const float4*)src;
    float4 hi = *(const float4*)(src + 4);
    uint4 pk;
    pk.x = cvtpk(lo.x, lo.y);
    pk.y = cvtpk(lo.z, lo.w);
    pk.z = cvtpk(hi.x, hi.y);
    pk.w = cvtpk(hi.z, hi.w);
    *(uint4*)(xo + (size_t)r * C_ + c8 * 8) = pk;
    unsigned short uu[8];
    uu[0] = (unsigned short)(pk.x & 0xffff); uu[1] = (unsigned short)(pk.x >> 16);
    uu[2] = (unsigned short)(pk.y & 0xffff); uu[3] = (unsigned short)(pk.y >> 16);
    uu[4] = (unsigned short)(pk.z & 0xffff); uu[5] = (unsigned short)(pk.z >> 16);
    uu[6] = (unsigned short)(pk.w & 0xffff); uu[7] = (unsigned short)(pk.w >> 16);
#pragma unroll
    for (int e = 0; e < 8; ++e)
      T[(c8 * 8 + e) * 73 + r] = (short)uu[e];
  }
  __syncthreads();

  __hip_bfloat16* vo = Vtg + ((size_t)(bh * D_)) * N_ + n0;
#pragma unroll
  for (int i = 0; i < 3; ++i) {
    int v = tid + 256 * i;         // 0..767
    int d = v >> 3, ncc = v & 7;   // d-row, 8-n group
    bf16x8 val = *(const bf16x8*)(T + d * 73 + ncc * 8);
    *(bf16x8*)(vo + (size_t)d * N_ + ncc * 8) = val;
  }
}

__global__ __launch_bounds__(256) void k_castw(const float* __restrict__ w,
                                               __hip_bfloat16* __restrict__ Wbf) {
  const int i = blockIdx.x * 256 + threadIdx.x;
  float4 f = *(const float4*)(w + (size_t)i * 4);
  uint2 pk;
  pk.x = cvtpk(f.x, f.y);
  pk.y = cvtpk(f.z, f.w);
  *(uint2*)(Wbf + (size_t)i * 4) = pk;
}

static __device__ __forceinline__ bf16x8 scale8(bf16x8 v, float s) {
  float f[8];
#pragma unroll
  for (int e = 0; e < 8; ++e) f[e] = tof(v[e]) * s;
  u32x4 pw;
  pw.x = cvtpk(f[0], f[1]);
  pw.y = cvtpk(f[2], f[3]);
  pw.z = cvtpk(f[4], f[5]);
  pw.w = cvtpk(f[6], f[7]);
  return __builtin_bit_cast(bf16x8, pw);
}

// ---------------------------------------------------------------------------
// flash attention v9 (frozen): 8 waves = 4 q-subtiles x 2 kv-groups;
// q-tile 128; kv 64/iter via global_load_lds; 32x32x16 MFMA; in-reg P
// (cvt_pk + permlane32_swap); no online max; LDS-combine epilogue;
// setprio around MFMA clusters; packed pair-sum psum.
// ---------------------------------------------------------------------------
__global__ __launch_bounds__(512, 4) void k_attn(const __hip_bfloat16* __restrict__ Xbf,
                                                 const __hip_bfloat16* __restrict__ Vtg,
                                                 __hip_bfloat16* __restrict__ Ybf) {
  __shared__ __align__(16) short SMs[27648];

  const int tid = threadIdx.x;
  const int wid = tid >> 6, lane = tid & 63;
  const int qsub = wid & 3, grp = wid >> 2;
  const int lr = lane & 31, hi = lane >> 5;
  const int qt = blockIdx.x, bh = blockIdx.y;
  const int b = bh >> 3, h = bh & 7;
  const int q0w = qt * 128 + qsub * 32;
  const float SL2E = 0.14724444f;  // log2(e)/sqrt(96)

  bf16x8 qf[6];
  {
    const __hip_bfloat16* qp =
        Xbf + ((size_t)(b * N_ + q0w + lr)) * C_ + h * D_ + hi * 8;
#pragma unroll
    for (int kk = 0; kk < 6; ++kk)
      qf[kk] = scale8(*(const bf16x8*)(qp + kk * 16), SL2E);
  }

  const short* Kbase = (const short*)(Xbf + ((size_t)b * N_) * C_ + h * D_);
  const short* Vbase = (const short*)(Vtg + ((size_t)bh * D_) * N_);

  const short* gsrc[4];
#pragma unroll
  for (int j = 0; j < 4; ++j) {
    const int t = wid + 8 * j;
    gsrc[j] = Kbase;
    if (t < 13) {
      int pc = t * 64 + lane;
      int r = pc / 13, ch = pc % 13;
      if (ch >= 12) ch = 0;
      gsrc[j] = Kbase + (size_t)r * C_ + ch * 8;
    } else if (t < 27) {
      int vc = t * 64 + lane - 832;
      int r = vc / 9, ch = vc % 9;
      if (vc >= 864) { r = 0; ch = 0; }
      if (ch >= 8) ch = 0;
      gsrc[j] = Vbase + (size_t)r * N_ + ch * 8;
    }
  }
  auto ldsb = (__attribute__((address_space(3))) short*)SMs;
  auto stage = [&](int nb) {
#pragma unroll
    for (int j = 0; j < 4; ++j) {
      const int t = wid + 8 * j;
      if (t < 27) {
        gload16(gsrc[j], ldsb + nb * 13824 + t * 512);
        gsrc[j] += (t < 13) ? 64 * C_ : 64;
      }
    }
  };

  stage(0);
  __syncthreads();

  f32x16 accO[3] = {};
  float lrun = 0.f;
  const int kro = (grp * 32 + lr) * 104 + hi * 8;
  const int vro = 6656 + lr * 72 + grp * 32 + hi * 8;

  int cur = 0;
  for (int it = 0; it < N_ / 64; ++it) {
    if (it < N_ / 64 - 1) stage(cur ^ 1);

    const short* Kw = SMs + cur * 13824 + kro;
    f32x16 accS = {};
    __builtin_amdgcn_s_setprio(1);
#pragma unroll
    for (int kk = 0; kk < 6; ++kk) {
      bf16x8 kf = *(const bf16x8*)(Kw + kk * 16);
      accS = __builtin_amdgcn_mfma_f32_32x32x16_bf16(kf, qf[kk], accS, 0, 0, 0);
    }
    __builtin_amdgcn_s_setprio(0);

#pragma unroll
    for (int r = 0; r < 16; ++r) accS[r] = exp2f(accS[r]);
    f32x2 psA = {0.f, 0.f}, psB = {0.f, 0.f};
#pragma unroll
    for (int r = 0; r < 16; r += 4) {
      f32x2 a; a.x = accS[r]; a.y = accS[r + 1];
      f32x2 c; c.x = accS[r + 2]; c.y = accS[r + 3];
      psA += a;
      psB += c;
    }
    psA += psB;
    lrun += psA.x + psA.y;

    bf16x8 pbf[2];
#pragma unroll
    for (int s = 0; s < 2; ++s) {
      unsigned lo0 = cvtpk(accS[8 * s + 0], accS[8 * s + 1]);
      unsigned lo1 = cvtpk(accS[8 * s + 2], accS[8 * s + 3]);
      unsigned hi0 = cvtpk(accS[8 * s + 4], accS[8 * s + 5]);
      unsigned hi1 = cvtpk(accS[8 * s + 6], accS[8 * s + 7]);
      asm volatile("v_permlane32_swap_b32 %0, %1" : "+v"(lo0), "+v"(hi0));
      asm volatile("v_permlane32_swap_b32 %0, %1" : "+v"(lo1), "+v"(hi1));
      u32x4 pw;
      pw.x = lo0; pw.y = lo1; pw.z = hi0; pw.w = hi1;
      pbf[s] = __builtin_bit_cast(bf16x8, pw);
    }

    const short* Vw = SMs + cur * 13824 + vro;
    __builtin_amdgcn_s_setprio(1);
#pragma unroll
    for (int s = 0; s < 2; ++s) {
#pragma unroll
      for (int dt = 0; dt < 3; ++dt) {
        bf16x8 va = *(const bf16x8*)(Vw + dt * 32 * 72 + s * 16);
        accO[dt] = __builtin_amdgcn_mfma_f32_32x32x16_bf16(va, pbf[s], accO[dt], 0, 0, 0);
      }
    }
    __builtin_amdgcn_s_setprio(0);

    __syncthreads();
    cur ^= 1;
  }

  float* Osh = (float*)SMs;
  float* lsh = (float*)SMs + 12288;
  if (grp == 0) {
#pragma unroll
    for (int dt = 0; dt < 3; ++dt)
#pragma unroll
      for (int r = 0; r < 16; ++r) {
        int dloc = (r & 3) + 8 * (r >> 2) + 4 * hi;
        Osh[(qsub * 96 + dt * 32 + dloc) * 32 + lr] = accO[dt][r];
      }
    lsh[qsub * 64 + lane] = lrun;
  }
  __syncthreads();
  if (grp == 1) {
    lrun += lsh[qsub * 64 + lane];
    float ltot = lrun + __shfl_xor(lrun, 32);
    float linv = 1.0f / ltot;
    __hip_bfloat16* yb =
        Ybf + ((size_t)(b * N_ + q0w + lr)) * C_ + h * D_ + hi * 4;
#pragma unroll
    for (int dt = 0; dt < 3; ++dt) {
#pragma unroll
      for (int rg = 0; rg < 4; ++rg) {
        float v0 = (accO[dt][rg * 4 + 0] +
                    Osh[(qsub * 96 + dt * 32 + 8 * rg + 4 * hi + 0) * 32 + lr]) * linv;
        float v1 = (accO[dt][rg * 4 + 1] +
                    Osh[(qsub * 96 + dt * 32 + 8 * rg + 4 * hi + 1) * 32 + lr]) * linv;
        float v2 = (accO[dt][rg * 4 + 2] +
                    Osh[(qsub * 96 + dt * 32 + 8 * rg + 4 * hi + 2) * 32 + lr]) * linv;
        float v3 = (accO[dt][rg * 4 + 3] +
                    Osh[(qsub * 96 + dt * 32 + 8 * rg + 4 * hi + 3) * 32 + lr]) * linv;
        uint2 st;
        st.x = cvtpk(v0, v1);
        st.y = cvtpk(v2, v3);
        *(uint2*)(yb + dt * 32 + rg * 8) = st;
      }
    }
  }
}

// ---------------------------------------------------------------------------
// projection (reverted to proven v8): 128x128 tile, BK=32, 4 waves x (64x64)
// ---------------------------------------------------------------------------
__global__ __launch_bounds__(256) void k_proj(const __hip_bfloat16* __restrict__ Ybf,
                                              const __hip_bfloat16* __restrict__ Wbf,
                                              const float* __restrict__ bias,
                                              float* __restrict__ out) {
  __shared__ __hip_bfloat16 Alds[128][40];
  __shared__ __hip_bfloat16 Blds[128][40];
  const int tid = threadIdx.x, wid = tid >> 6, lane = tid & 63;
  const int lr = lane & 15, lg = lane >> 4;
  const int m0 = blockIdx.x * 128, n0 = blockIdx.y * 128;
  const int wm = (wid >> 1) * 64, wn = (wid & 1) * 64;

  const f32x4 fzero = {0.f, 0.f, 0.f, 0.f};
  f32x4 acc[4][4];
#pragma unroll
  for (int mi = 0; mi < 4; ++mi)
#pragma unroll
    for (int ni = 0; ni < 4; ++ni) acc[mi][ni] = fzero;

  for (int k0 = 0; k0 < C_; k0 += 32) {
#pragma unroll
    for (int i = 0; i < 2; ++i) {
      int idx = tid + i * 256;
      int r = idx >> 2, cc = idx & 3;
      *(bf16x8*)(&Alds[r][cc * 8]) =
          *(const bf16x8*)(Ybf + (size_t)(m0 + r) * C_ + k0 + cc * 8);
      *(bf16x8*)(&Blds[r][cc * 8]) =
          *(const bf16x8*)(Wbf + (size_t)(n0 + r) * C_ + k0 + cc * 8);
    }
    __syncthreads();
    bf16x8 af[4], bfr[4];
#pragma unroll
    for (int i = 0; i < 4; ++i) {
      af[i] = *(const bf16x8*)(&Alds[wm + i * 16 + lr][lg * 8]);
      bfr[i] = *(const bf16x8*)(&Blds[wn + i * 16 + lr][lg * 8]);
    }
#pragma unroll
    for (int mi = 0; mi < 4; ++mi)
#pragma unroll
      for (int ni = 0; ni < 4; ++ni)
        acc[mi][ni] = __builtin_amdgcn_mfma_f32_16x16x32_bf16(af[mi], bfr[ni], acc[mi][ni], 0, 0, 0);
    __syncthreads();
  }

#pragma unroll
  for (int mi = 0; mi < 4; ++mi) {
#pragma unroll
    for (int ni = 0; ni < 4; ++ni) {
      int col = n0 + wn + ni * 16 + lr;
      float bv = bias[col];
#pragma unroll
      for (int j = 0; j < 4; ++j) {
        int row = m0 + wm + mi * 16 + lg * 4 + j;
        out[(size_t)row * C_ + col] = acc[mi][ni][j] + bv;
      }
    }
  }
}

extern "C" void kernel_launch(void* const* d_in, const int* in_sizes, int n_in,
                              void* d_out, int out_size, void* d_ws, size_t ws_size,
                              hipStream_t stream) {
  const float* x = (const float*)d_in[0];
  const float* pw = (const float*)d_in[1];
  const float* pb = (const float*)d_in[2];
  float* out = (float*)d_out;

  __hip_bfloat16* Xbf = (__hip_bfloat16*)d_ws;
  __hip_bfloat16* Vtg = Xbf + (size_t)B_ * N_ * C_;
  __hip_bfloat16* Wbf = Vtg + (size_t)B_ * N_ * C_;
  __hip_bfloat16* Ybf = Wbf + (size_t)C_ * C_;

  k_prep<<<dim3(N_ / 64, B_ * H_), 256, 0, stream>>>(x, Xbf, Vtg);
  k_castw<<<(C_ * C_ / 4) / 256, 256, 0, stream>>>(pw, Wbf);
  k_attn<<<dim3(N_ / 128, B_ * H_), 512, 0, stream>>>(Xbf, Vtg, Ybf);
  k_proj<<<dim3((B_ * N_) / 128, C_ / 128), 256, 0, stream>>>(Ybf, Wbf, pb, out);
}

// Round 11
// 104.631 us; speedup vs baseline: 1.1032x; 1.0210x over previous
//
#include <hip/hip_runtime.h>
#include <hip/hip_bf16.h>

#define B_ 4
#define N_ 2048
#define C_ 768
#define H_ 8
#define D_ 96

typedef __attribute__((ext_vector_type(8))) short bf16x8;
typedef __attribute__((ext_vector_type(2))) float f32x2;
typedef __attribute__((ext_vector_type(4))) float f32x4;
typedef __attribute__((ext_vector_type(16))) float f32x16;
typedef __attribute__((ext_vector_type(4))) unsigned u32x4;

static __device__ __forceinline__ unsigned cvtpk(float lo, float hi) {
  unsigned r;
  asm("v_cvt_pk_bf16_f32 %0, %1, %2" : "=v"(r) : "v"(lo), "v"(hi));
  return r;
}
static __device__ __forceinline__ float tof(short u) {
  return __bfloat162float(__builtin_bit_cast(__hip_bfloat16, (unsigned short)u));
}
static __device__ __forceinline__ void gload16(const void* g,
                                               const __attribute__((address_space(3))) short* l) {
  __builtin_amdgcn_global_load_lds(
      (const __attribute__((address_space(1))) void*)g,
      (__attribute__((address_space(3))) void*)l, 16, 0, 0);
}

// ---------------------------------------------------------------------------
// prep v3 (fused): blocks with bh<32: cast x->Xbf + build Vtg via padded LDS
// transpose tile. Blocks with bh==32: cast proj_w -> Wbf (18 float4/thread).
// ---------------------------------------------------------------------------
__global__ __launch_bounds__(256) void k_prep(const float* __restrict__ x,
                                              const float* __restrict__ w,
                                              __hip_bfloat16* __restrict__ Xbf,
                                              __hip_bfloat16* __restrict__ Vtg,
                                              __hip_bfloat16* __restrict__ Wbf) {
  __shared__ short T[96 * 73];
  const int tid = threadIdx.x;
  const int nc = blockIdx.x, bh = blockIdx.y;

  if (bh == 32) {  // W cast: 147456 float4s over 8192 threads x 18
    int i0 = nc * 256 + tid;
#pragma unroll
    for (int e = 0; e < 18; ++e) {
      int i = i0 + e * 8192;
      float4 f = *(const float4*)(w + (size_t)i * 4);
      uint2 pk;
      pk.x = cvtpk(f.x, f.y);
      pk.y = cvtpk(f.z, f.w);
      *(uint2*)(Wbf + (size_t)i * 4) = pk;
    }
    return;
  }

  const int b = bh >> 3, h = bh & 7;
  const int n0 = nc * 64;
  const float* xb = x + ((size_t)(b * N_ + n0)) * C_ + h * D_;
  __hip_bfloat16* xo = Xbf + ((size_t)(b * N_ + n0)) * C_ + h * D_;

#pragma unroll
  for (int i = 0; i < 3; ++i) {
    int c = tid + 256 * i;          // 0..767 chunk id
    int r = c / 12, c8 = c % 12;    // n-row r, 8-col group c8
    const float* src = xb + (size_t)r * C_ + c8 * 8;
    float4 lo = *(const float4*)src;
    float4 hi = *(const float4*)(src + 4);
    uint4 pk;
    pk.x = cvtpk(lo.x, lo.y);
    pk.y = cvtpk(lo.z, lo.w);
    pk.z = cvtpk(hi.x, hi.y);
    pk.w = cvtpk(hi.z, hi.w);
    *(uint4*)(xo + (size_t)r * C_ + c8 * 8) = pk;
    unsigned short uu[8];
    uu[0] = (unsigned short)(pk.x & 0xffff); uu[1] = (unsigned short)(pk.x >> 16);
    uu[2] = (unsigned short)(pk.y & 0xffff); uu[3] = (unsigned short)(pk.y >> 16);
    uu[4] = (unsigned short)(pk.z & 0xffff); uu[5] = (unsigned short)(pk.z >> 16);
    uu[6] = (unsigned short)(pk.w & 0xffff); uu[7] = (unsigned short)(pk.w >> 16);
#pragma unroll
    for (int e = 0; e < 8; ++e)
      T[(c8 * 8 + e) * 73 + r] = (short)uu[e];
  }
  __syncthreads();

  __hip_bfloat16* vo = Vtg + ((size_t)(bh * D_)) * N_ + n0;
#pragma unroll
  for (int i = 0; i < 3; ++i) {
    int v = tid + 256 * i;         // 0..767
    int d = v >> 3, ncc = v & 7;   // d-row, 8-n group
    bf16x8 val = *(const bf16x8*)(T + d * 73 + ncc * 8);
    *(bf16x8*)(vo + (size_t)d * N_ + ncc * 8) = val;
  }
}

static __device__ __forceinline__ bf16x8 scale8(bf16x8 v, float s) {
  float f[8];
#pragma unroll
  for (int e = 0; e < 8; ++e) f[e] = tof(v[e]) * s;
  u32x4 pw;
  pw.x = cvtpk(f[0], f[1]);
  pw.y = cvtpk(f[2], f[3]);
  pw.z = cvtpk(f[4], f[5]);
  pw.w = cvtpk(f[6], f[7]);
  return __builtin_bit_cast(bf16x8, pw);
}

// ---------------------------------------------------------------------------
// flash attention v9 (frozen): 8 waves = 4 q-subtiles x 2 kv-groups;
// q-tile 128; kv 64/iter via global_load_lds; 32x32x16 MFMA; in-reg P
// (cvt_pk + permlane32_swap); no online max; LDS-combine epilogue;
// setprio around MFMA clusters; packed pair-sum psum.
// ---------------------------------------------------------------------------
__global__ __launch_bounds__(512, 4) void k_attn(const __hip_bfloat16* __restrict__ Xbf,
                                                 const __hip_bfloat16* __restrict__ Vtg,
                                                 __hip_bfloat16* __restrict__ Ybf) {
  __shared__ __align__(16) short SMs[27648];

  const int tid = threadIdx.x;
  const int wid = tid >> 6, lane = tid & 63;
  const int qsub = wid & 3, grp = wid >> 2;
  const int lr = lane & 31, hi = lane >> 5;
  const int qt = blockIdx.x, bh = blockIdx.y;
  const int b = bh >> 3, h = bh & 7;
  const int q0w = qt * 128 + qsub * 32;
  const float SL2E = 0.14724444f;  // log2(e)/sqrt(96)

  bf16x8 qf[6];
  {
    const __hip_bfloat16* qp =
        Xbf + ((size_t)(b * N_ + q0w + lr)) * C_ + h * D_ + hi * 8;
#pragma unroll
    for (int kk = 0; kk < 6; ++kk)
      qf[kk] = scale8(*(const bf16x8*)(qp + kk * 16), SL2E);
  }

  const short* Kbase = (const short*)(Xbf + ((size_t)b * N_) * C_ + h * D_);
  const short* Vbase = (const short*)(Vtg + ((size_t)bh * D_) * N_);

  const short* gsrc[4];
#pragma unroll
  for (int j = 0; j < 4; ++j) {
    const int t = wid + 8 * j;
    gsrc[j] = Kbase;
    if (t < 13) {
      int pc = t * 64 + lane;
      int r = pc / 13, ch = pc % 13;
      if (ch >= 12) ch = 0;
      gsrc[j] = Kbase + (size_t)r * C_ + ch * 8;
    } else if (t < 27) {
      int vc = t * 64 + lane - 832;
      int r = vc / 9, ch = vc % 9;
      if (vc >= 864) { r = 0; ch = 0; }
      if (ch >= 8) ch = 0;
      gsrc[j] = Vbase + (size_t)r * N_ + ch * 8;
    }
  }
  auto ldsb = (__attribute__((address_space(3))) short*)SMs;
  auto stage = [&](int nb) {
#pragma unroll
    for (int j = 0; j < 4; ++j) {
      const int t = wid + 8 * j;
      if (t < 27) {
        gload16(gsrc[j], ldsb + nb * 13824 + t * 512);
        gsrc[j] += (t < 13) ? 64 * C_ : 64;
      }
    }
  };

  stage(0);
  __syncthreads();

  f32x16 accO[3] = {};
  float lrun = 0.f;
  const int kro = (grp * 32 + lr) * 104 + hi * 8;
  const int vro = 6656 + lr * 72 + grp * 32 + hi * 8;

  int cur = 0;
  for (int it = 0; it < N_ / 64; ++it) {
    if (it < N_ / 64 - 1) stage(cur ^ 1);

    const short* Kw = SMs + cur * 13824 + kro;
    f32x16 accS = {};
    __builtin_amdgcn_s_setprio(1);
#pragma unroll
    for (int kk = 0; kk < 6; ++kk) {
      bf16x8 kf = *(const bf16x8*)(Kw + kk * 16);
      accS = __builtin_amdgcn_mfma_f32_32x32x16_bf16(kf, qf[kk], accS, 0, 0, 0);
    }
    __builtin_amdgcn_s_setprio(0);

#pragma unroll
    for (int r = 0; r < 16; ++r) accS[r] = exp2f(accS[r]);
    f32x2 psA = {0.f, 0.f}, psB = {0.f, 0.f};
#pragma unroll
    for (int r = 0; r < 16; r += 4) {
      f32x2 a; a.x = accS[r]; a.y = accS[r + 1];
      f32x2 c; c.x = accS[r + 2]; c.y = accS[r + 3];
      psA += a;
      psB += c;
    }
    psA += psB;
    lrun += psA.x + psA.y;

    bf16x8 pbf[2];
#pragma unroll
    for (int s = 0; s < 2; ++s) {
      unsigned lo0 = cvtpk(accS[8 * s + 0], accS[8 * s + 1]);
      unsigned lo1 = cvtpk(accS[8 * s + 2], accS[8 * s + 3]);
      unsigned hi0 = cvtpk(accS[8 * s + 4], accS[8 * s + 5]);
      unsigned hi1 = cvtpk(accS[8 * s + 6], accS[8 * s + 7]);
      asm volatile("v_permlane32_swap_b32 %0, %1" : "+v"(lo0), "+v"(hi0));
      asm volatile("v_permlane32_swap_b32 %0, %1" : "+v"(lo1), "+v"(hi1));
      u32x4 pw;
      pw.x = lo0; pw.y = lo1; pw.z = hi0; pw.w = hi1;
      pbf[s] = __builtin_bit_cast(bf16x8, pw);
    }

    const short* Vw = SMs + cur * 13824 + vro;
    __builtin_amdgcn_s_setprio(1);
#pragma unroll
    for (int s = 0; s < 2; ++s) {
#pragma unroll
      for (int dt = 0; dt < 3; ++dt) {
        bf16x8 va = *(const bf16x8*)(Vw + dt * 32 * 72 + s * 16);
        accO[dt] = __builtin_amdgcn_mfma_f32_32x32x16_bf16(va, pbf[s], accO[dt], 0, 0, 0);
      }
    }
    __builtin_amdgcn_s_setprio(0);

    __syncthreads();
    cur ^= 1;
  }

  float* Osh = (float*)SMs;
  float* lsh = (float*)SMs + 12288;
  if (grp == 0) {
#pragma unroll
    for (int dt = 0; dt < 3; ++dt)
#pragma unroll
      for (int r = 0; r < 16; ++r) {
        int dloc = (r & 3) + 8 * (r >> 2) + 4 * hi;
        Osh[(qsub * 96 + dt * 32 + dloc) * 32 + lr] = accO[dt][r];
      }
    lsh[qsub * 64 + lane] = lrun;
  }
  __syncthreads();
  if (grp == 1) {
    lrun += lsh[qsub * 64 + lane];
    float ltot = lrun + __shfl_xor(lrun, 32);
    float linv = 1.0f / ltot;
    __hip_bfloat16* yb =
        Ybf + ((size_t)(b * N_ + q0w + lr)) * C_ + h * D_ + hi * 4;
#pragma unroll
    for (int dt = 0; dt < 3; ++dt) {
#pragma unroll
      for (int rg = 0; rg < 4; ++rg) {
        float v0 = (accO[dt][rg * 4 + 0] +
                    Osh[(qsub * 96 + dt * 32 + 8 * rg + 4 * hi + 0) * 32 + lr]) * linv;
        float v1 = (accO[dt][rg * 4 + 1] +
                    Osh[(qsub * 96 + dt * 32 + 8 * rg + 4 * hi + 1) * 32 + lr]) * linv;
        float v2 = (accO[dt][rg * 4 + 2] +
                    Osh[(qsub * 96 + dt * 32 + 8 * rg + 4 * hi + 2) * 32 + lr]) * linv;
        float v3 = (accO[dt][rg * 4 + 3] +
                    Osh[(qsub * 96 + dt * 32 + 8 * rg + 4 * hi + 3) * 32 + lr]) * linv;
        uint2 st;
        st.x = cvtpk(v0, v1);
        st.y = cvtpk(v2, v3);
        *(uint2*)(yb + dt * 32 + rg * 8) = st;
      }
    }
  }
}

// ---------------------------------------------------------------------------
// projection v3: 128x128 tile, BK=32, double-buffered reg-staged LDS
// (load next -> compute cur -> write next -> one barrier). Grid n-tile-fast
// so 6 consecutive blocks share the A-panel in L2.
// ---------------------------------------------------------------------------
__global__ __launch_bounds__(256) void k_proj(const __hip_bfloat16* __restrict__ Ybf,
                                              const __hip_bfloat16* __restrict__ Wbf,
                                              const float* __restrict__ bias,
                                              float* __restrict__ out) {
  __shared__ __hip_bfloat16 Alds[2][128][40];
  __shared__ __hip_bfloat16 Blds[2][128][40];
  const int tid = threadIdx.x, wid = tid >> 6, lane = tid & 63;
  const int lr = lane & 15, lg = lane >> 4;
  const int n0 = blockIdx.x * 128, m0 = blockIdx.y * 128;
  const int wm = (wid >> 1) * 64, wn = (wid & 1) * 64;

  // staging descriptors: 4 chunks/thread (2 A + 2 B)
  int sr[2], sc[2];
#pragma unroll
  for (int i = 0; i < 2; ++i) {
    int idx = tid + i * 256;
    sr[i] = idx >> 2;
    sc[i] = idx & 3;
  }
  bf16x8 sa[2], sb[2];
  auto stage_load = [&](int k0) {
#pragma unroll
    for (int i = 0; i < 2; ++i) {
      sa[i] = *(const bf16x8*)(Ybf + (size_t)(m0 + sr[i]) * C_ + k0 + sc[i] * 8);
      sb[i] = *(const bf16x8*)(Wbf + (size_t)(n0 + sr[i]) * C_ + k0 + sc[i] * 8);
    }
  };
  auto stage_write = [&](int buf) {
#pragma unroll
    for (int i = 0; i < 2; ++i) {
      *(bf16x8*)(&Alds[buf][sr[i]][sc[i] * 8]) = sa[i];
      *(bf16x8*)(&Blds[buf][sr[i]][sc[i] * 8]) = sb[i];
    }
  };

  const f32x4 fzero = {0.f, 0.f, 0.f, 0.f};
  f32x4 acc[4][4];
#pragma unroll
  for (int mi = 0; mi < 4; ++mi)
#pragma unroll
    for (int ni = 0; ni < 4; ++ni) acc[mi][ni] = fzero;

  stage_load(0);
  stage_write(0);
  __syncthreads();

  int cur = 0;
  for (int k0 = 0; k0 < C_; k0 += 32) {
    const bool more = (k0 + 32) < C_;
    if (more) stage_load(k0 + 32);

    bf16x8 af[4], bfr[4];
#pragma unroll
    for (int i = 0; i < 4; ++i) {
      af[i] = *(const bf16x8*)(&Alds[cur][wm + i * 16 + lr][lg * 8]);
      bfr[i] = *(const bf16x8*)(&Blds[cur][wn + i * 16 + lr][lg * 8]);
    }
#pragma unroll
    for (int mi = 0; mi < 4; ++mi)
#pragma unroll
      for (int ni = 0; ni < 4; ++ni)
        acc[mi][ni] = __builtin_amdgcn_mfma_f32_16x16x32_bf16(af[mi], bfr[ni], acc[mi][ni], 0, 0, 0);

    if (more) stage_write(cur ^ 1);
    __syncthreads();
    cur ^= 1;
  }

#pragma unroll
  for (int mi = 0; mi < 4; ++mi) {
#pragma unroll
    for (int ni = 0; ni < 4; ++ni) {
      int col = n0 + wn + ni * 16 + lr;
      float bv = bias[col];
#pragma unroll
      for (int j = 0; j < 4; ++j) {
        int row = m0 + wm + mi * 16 + lg * 4 + j;
        out[(size_t)row * C_ + col] = acc[mi][ni][j] + bv;
      }
    }
  }
}

extern "C" void kernel_launch(void* const* d_in, const int* in_sizes, int n_in,
                              void* d_out, int out_size, void* d_ws, size_t ws_size,
                              hipStream_t stream) {
  const float* x = (const float*)d_in[0];
  const float* pw = (const float*)d_in[1];
  const float* pb = (const float*)d_in[2];
  float* out = (float*)d_out;

  __hip_bfloat16* Xbf = (__hip_bfloat16*)d_ws;
  __hip_bfloat16* Vtg = Xbf + (size_t)B_ * N_ * C_;
  __hip_bfloat16* Wbf = Vtg + (size_t)B_ * N_ * C_;
  __hip_bfloat16* Ybf = Wbf + (size_t)C_ * C_;

  k_prep<<<dim3(N_ / 64, B_ * H_ + 1), 256, 0, stream>>>(x, pw, Xbf, Vtg, Wbf);
  k_attn<<<dim3(N_ / 128, B_ * H_), 512, 0, stream>>>(Xbf, Vtg, Ybf);
  k_proj<<<dim3(C_ / 128, (B_ * N_) / 128), 256, 0, stream>>>(Ybf, Wbf, pb, out);
}